// Round 1
// baseline (364.921 us; speedup 1.0000x reference)
//
#include <hip/hip_runtime.h>
#include <math.h>

// ---------------------------------------------------------------------------
// A3TGCN2 collapsed:
//   H0 == 0 in every cell invocation =>
//     out[n,o] = sum_t p[t] * (1 - sigmoid(pre_z[n,t,o])) * tanh(pre_h[n,t,o])
//     pre_g[n,t,o] = sum_f Agg(X)[n,f,t] * Mg[o,f] + cg[o]
//     Mg = Lg[:, :O] @ Wg   (32x32),  cg = Lg[:, :O] @ bg + lg_b
//   Agg = symmetric-normalized adjacency with self loops, applied ONCE to the
//   raw X[n, F_IN, T] payload (256 floats / node).
// ---------------------------------------------------------------------------

__global__ void k_init(float* __restrict__ deg, int* __restrict__ cnt, int n) {
  int i = blockIdx.x * blockDim.x + threadIdx.x;
  if (i < n) { deg[i] = 1.0f; cnt[i] = 0; }   // 1.0 = self-loop weight
}

__global__ void k_count(const int* __restrict__ ei, const float* __restrict__ ew,
                        float* __restrict__ deg, int* __restrict__ cnt, int E) {
  int e = blockIdx.x * blockDim.x + threadIdx.x;
  if (e < E) {
    int c = ei[E + e];                 // col (destination)
    atomicAdd(deg + c, ew[e]);
    atomicAdd(cnt + c, 1);
  }
}

__global__ void k_dinv(const float* __restrict__ deg, float* __restrict__ dinv, int n) {
  int i = blockIdx.x * blockDim.x + threadIdx.x;
  if (i < n) dinv[i] = rsqrtf(deg[i]);   // deg >= 1 always (self loop)
}

__global__ __launch_bounds__(1024) void k_scan(const int* __restrict__ cnt,
                                               int* __restrict__ row_start,
                                               int* __restrict__ cursor,
                                               int n, int E) {
  __shared__ int ssum[1024];
  int tid = threadIdx.x;
  int chunk = (n + 1023) >> 10;
  int lo = tid * chunk;
  int hi = lo + chunk; if (hi > n) hi = n; if (lo > n) lo = n;
  int s = 0;
  for (int i = lo; i < hi; ++i) s += cnt[i];
  ssum[tid] = s;
  __syncthreads();
  for (int off = 1; off < 1024; off <<= 1) {
    int v = (tid >= off) ? ssum[tid - off] : 0;
    __syncthreads();
    ssum[tid] += v;
    __syncthreads();
  }
  int run = (tid == 0) ? 0 : ssum[tid - 1];
  for (int i = lo; i < hi; ++i) {
    row_start[i] = run;
    cursor[i]    = run;
    run += cnt[i];
  }
  if (tid == 0) row_start[n] = E;
}

__global__ void k_scatter(const int* __restrict__ ei, const float* __restrict__ ew,
                          const float* __restrict__ dinv, int* __restrict__ cursor,
                          int* __restrict__ csr_src, float* __restrict__ csr_w, int E) {
  int e = blockIdx.x * blockDim.x + threadIdx.x;
  if (e < E) {
    int r = ei[e];
    int c = ei[E + e];
    int pos = atomicAdd(cursor + c, 1);
    csr_src[pos] = r;
    csr_w[pos]   = ew[e] * dinv[r];   // dinv[col] applied at the end
  }
}

__global__ __launch_bounds__(1024) void k_prep(
    const float* __restrict__ Wz, const float* __restrict__ bz,
    const float* __restrict__ Wh, const float* __restrict__ bh,
    const float* __restrict__ Lz, const float* __restrict__ lzb,
    const float* __restrict__ Lh, const float* __restrict__ lhb,
    const float* __restrict__ att,
    float* __restrict__ Mt, float* __restrict__ cvec, float* __restrict__ p) {
  int g = blockIdx.x;          // 0 = z-gate, 1 = h-gate
  int tid = threadIdx.x;       // 1024: tid = f*32 + o
  const float* L  = g ? Lh  : Lz;
  const float* W  = g ? Wh  : Wz;
  const float* b  = g ? bh  : bz;
  const float* lb = g ? lhb : lzb;
  int f = tid >> 5, o = tid & 31;
  float s = 0.f;
  for (int k = 0; k < 32; ++k) s += L[o * 64 + k] * W[k * 32 + f];
  Mt[g * 1024 + f * 32 + o] = s;          // transposed: [g][f][o]
  if (tid < 32) {
    float c = lb[tid];
    for (int k = 0; k < 32; ++k) c += L[tid * 64 + k] * b[k];
    cvec[g * 32 + tid] = c;
  }
  if (g == 0 && tid == 0) {
    float m = att[0];
    for (int t = 1; t < 8; ++t) m = fmaxf(m, att[t]);
    float e8[8], sm = 0.f;
    for (int t = 0; t < 8; ++t) { e8[t] = expf(att[t] - m); sm += e8[t]; }
    for (int t = 0; t < 8; ++t) p[t] = e8[t] / sm;
  }
}

// One wave (64 lanes) per node. Lane l owns X-row elements [4l, 4l+4).
__global__ __launch_bounds__(64) void k_main(
    const float* __restrict__ X, const int* __restrict__ row_start,
    const int* __restrict__ csr_src, const float* __restrict__ csr_w,
    const float* __restrict__ dinv, const float* __restrict__ Mt,
    const float* __restrict__ cvec, const float* __restrict__ p,
    float* __restrict__ out) {
  int node = blockIdx.x;
  int l = threadIdx.x;
  __shared__ float ax[256];

  float di = dinv[node];
  const float4* Xv = (const float4*)X;   // 64 float4 per node row (1 KB)

  // self-loop contribution: dinv^2 * X[node]  (one dinv applied at the end)
  float4 a = Xv[(size_t)node * 64 + l];
  float4 acc = make_float4(di * a.x, di * a.y, di * a.z, di * a.w);

  int jlo = row_start[node], jhi = row_start[node + 1];
  int j = jlo;
  for (; j + 1 < jhi; j += 2) {
    int   s0 = csr_src[j],  s1 = csr_src[j + 1];
    float w0 = csr_w[j],    w1 = csr_w[j + 1];
    float4 x0 = Xv[(size_t)s0 * 64 + l];
    float4 x1 = Xv[(size_t)s1 * 64 + l];
    acc.x += w0 * x0.x; acc.y += w0 * x0.y; acc.z += w0 * x0.z; acc.w += w0 * x0.w;
    acc.x += w1 * x1.x; acc.y += w1 * x1.y; acc.z += w1 * x1.z; acc.w += w1 * x1.w;
  }
  if (j < jhi) {
    int   s0 = csr_src[j];
    float w0 = csr_w[j];
    float4 x0 = Xv[(size_t)s0 * 64 + l];
    acc.x += w0 * x0.x; acc.y += w0 * x0.y; acc.z += w0 * x0.z; acc.w += w0 * x0.w;
  }
  acc.x *= di; acc.y *= di; acc.z *= di; acc.w *= di;

  ((float4*)ax)[l] = acc;                // ax[f*8 + t] layout (X row layout)
  __syncthreads();

  int o = l & 31, g = l >> 5;
  float c = cvec[g * 32 + o];
  float pre[8];
#pragma unroll
  for (int t = 0; t < 8; ++t) pre[t] = c;

  const float*  M   = Mt + g * 1024;
  const float4* axv = (const float4*)ax;
#pragma unroll 8
  for (int f = 0; f < 32; ++f) {
    float  m  = M[f * 32 + o];           // coalesced 128B per half-wave, L1-hot
    float4 a0 = axv[f * 2];              // LDS broadcast reads
    float4 a1 = axv[f * 2 + 1];
    pre[0] = fmaf(m, a0.x, pre[0]); pre[1] = fmaf(m, a0.y, pre[1]);
    pre[2] = fmaf(m, a0.z, pre[2]); pre[3] = fmaf(m, a0.w, pre[3]);
    pre[4] = fmaf(m, a1.x, pre[4]); pre[5] = fmaf(m, a1.y, pre[5]);
    pre[6] = fmaf(m, a1.z, pre[6]); pre[7] = fmaf(m, a1.w, pre[7]);
  }

  float v[8];
  if (g == 0) {
#pragma unroll
    for (int t = 0; t < 8; ++t) v[t] = 1.f / (1.f + expf(pre[t]));  // 1 - sigmoid
  } else {
#pragma unroll
    for (int t = 0; t < 8; ++t) v[t] = tanhf(pre[t]);
  }

  float pv[8];
#pragma unroll
  for (int t = 0; t < 8; ++t) pv[t] = p[t];

  float res = 0.f;
#pragma unroll
  for (int t = 0; t < 8; ++t) {
    float other = __shfl(v[t], l ^ 32);  // pair z-half with h-half
    res += pv[t] * v[t] * other;
  }
  if (g == 0) out[(size_t)node * 32 + o] = res;
}

extern "C" void kernel_launch(void* const* d_in, const int* in_sizes, int n_in,
                              void* d_out, int out_size, void* d_ws, size_t ws_size,
                              hipStream_t stream) {
  const float* X   = (const float*)d_in[0];
  const int*   ei  = (const int*)d_in[1];    // (2,E) int32 (jax x64 off)
  const float* ew  = (const float*)d_in[2];
  const float* Wz  = (const float*)d_in[3];
  const float* bz  = (const float*)d_in[4];
  // d_in[5] = Wr, d_in[6] = br : dead (H*R == 0)
  const float* Wh  = (const float*)d_in[7];
  const float* bh  = (const float*)d_in[8];
  const float* Lz  = (const float*)d_in[9];
  const float* lzb = (const float*)d_in[10];
  // d_in[11] = Lr, d_in[12] = lr_b : dead
  const float* Lh  = (const float*)d_in[13];
  const float* lhb = (const float*)d_in[14];
  const float* att = (const float*)d_in[15];

  int N = in_sizes[0] / 256;   // F_IN * T = 256
  int E = in_sizes[2];

  char* w = (char*)d_ws;
  size_t off = 0;
  auto alloc = [&](size_t bytes) -> void* {
    void* pp = w + off;
    off = (off + bytes + 255) & ~(size_t)255;
    return pp;
  };
  float* deg       = (float*)alloc((size_t)N * 4);
  float* dinv      = (float*)alloc((size_t)N * 4);
  int*   cnt       = (int*)  alloc((size_t)N * 4);
  int*   row_start = (int*)  alloc((size_t)(N + 1) * 4);
  int*   cursor    = (int*)  alloc((size_t)N * 4);
  int*   csr_src   = (int*)  alloc((size_t)E * 4);
  float* csr_w     = (float*)alloc((size_t)E * 4);
  float* Mt        = (float*)alloc(2048 * 4);
  float* cvec      = (float*)alloc(64 * 4);
  float* p         = (float*)alloc(8 * 4);
  (void)ws_size; (void)n_in; (void)out_size;

  int nb_n = (N + 255) / 256;
  int nb_e = (E + 255) / 256;

  k_init   <<<nb_n, 256, 0, stream>>>(deg, cnt, N);
  k_count  <<<nb_e, 256, 0, stream>>>(ei, ew, deg, cnt, E);
  k_dinv   <<<nb_n, 256, 0, stream>>>(deg, dinv, N);
  k_scan   <<<1, 1024, 0, stream>>>(cnt, row_start, cursor, N, E);
  k_scatter<<<nb_e, 256, 0, stream>>>(ei, ew, dinv, cursor, csr_src, csr_w, E);
  k_prep   <<<2, 1024, 0, stream>>>(Wz, bz, Wh, bh, Lz, lzb, Lh, lhb, att,
                                    Mt, cvec, p);
  k_main   <<<N, 64, 0, stream>>>(X, row_start, csr_src, csr_w, dinv,
                                  Mt, cvec, p, (float*)d_out);
}

// Round 2
// 188.783 us; speedup vs baseline: 1.9330x; 1.9330x over previous
//
#include <hip/hip_runtime.h>
#include <hip/hip_fp16.h>
#include <math.h>

// ---------------------------------------------------------------------------
// A3TGCN2 collapsed (H0 == 0 in every cell):
//   out[n,o] = sum_t p[t] * (1 - sigmoid(pre_z[n,t,o])) * tanh(pre_h[n,t,o])
//   pre_g[n,t,o] = sum_f Agg(X)[n,f,t] * Mg[o,f] + cg[o]
//   Mg = Lg[:, :O] @ Wg (32x32), cg = Lg[:, :O] @ bg + lg_b
//   Agg = sym-normalized adjacency (+self loops) applied ONCE to raw X rows.
// This round: fp16 copy of X (fits aggregate L2), packed u64 deg|cnt atomic,
// multi-block scan, 8B-packed CSR scatter.
// ---------------------------------------------------------------------------

__global__ void k_init(unsigned long long* __restrict__ pk, int n) {
  int i = blockIdx.x * blockDim.x + threadIdx.x;
  if (i < n) pk[i] = 0ull;
}

// one u64 atomic per edge: high 32 = weight sum in 2^-24 fixed point, low 32 = count
__global__ void k_count(const int* __restrict__ ei, const float* __restrict__ ew,
                        unsigned long long* __restrict__ pk, int E) {
  int e = blockIdx.x * blockDim.x + threadIdx.x;
  if (e < E) {
    int c = ei[E + e];
    unsigned wfx = (unsigned)(ew[e] * 16777216.0f + 0.5f);
    atomicAdd(pk + c, ((unsigned long long)wfx << 32) | 1ull);
  }
}

// per-1024-node block: partial sums of counts + dinv
__global__ __launch_bounds__(256) void k_bsum(const unsigned long long* __restrict__ pk,
                                              float* __restrict__ dinv,
                                              int* __restrict__ bsum, int n) {
  int b = blockIdx.x, tid = threadIdx.x;
  int base = b * 1024 + tid * 4;
  int s = 0;
#pragma unroll
  for (int k = 0; k < 4; ++k) {
    int i = base + k;
    if (i < n) {
      unsigned long long v = pk[i];
      s += (int)(v & 0xffffffffull);
      float deg = (float)(v >> 32) * (1.0f / 16777216.0f) + 1.0f;  // +1 self loop
      dinv[i] = rsqrtf(deg);
    }
  }
  __shared__ int sm[256];
  sm[tid] = s;
  __syncthreads();
  for (int off = 128; off > 0; off >>= 1) {
    if (tid < off) sm[tid] += sm[tid + off];
    __syncthreads();
  }
  if (tid == 0) bsum[b] = sm[0];
}

__global__ __launch_bounds__(256) void k_bscan(const int* __restrict__ bsum,
                                               int* __restrict__ boff, int nb) {
  __shared__ int sm[256];
  int tid = threadIdx.x;
  sm[tid] = (tid < nb) ? bsum[tid] : 0;
  __syncthreads();
  for (int off = 1; off < 256; off <<= 1) {
    int v = (tid >= off) ? sm[tid - off] : 0;
    __syncthreads();
    sm[tid] += v;
    __syncthreads();
  }
  if (tid < nb) boff[tid] = tid ? sm[tid - 1] : 0;
}

__global__ __launch_bounds__(256) void k_offsets(const unsigned long long* __restrict__ pk,
                                                 const int* __restrict__ boff,
                                                 int* __restrict__ row_start,
                                                 int* __restrict__ cursor, int n, int E) {
  int b = blockIdx.x, tid = threadIdx.x;
  int base = b * 1024 + tid * 4;
  int c[4], s = 0;
#pragma unroll
  for (int k = 0; k < 4; ++k) {
    int i = base + k;
    c[k] = (i < n) ? (int)(pk[i] & 0xffffffffull) : 0;
    s += c[k];
  }
  __shared__ int sm[256];
  sm[tid] = s;
  __syncthreads();
  for (int off = 1; off < 256; off <<= 1) {
    int v = (tid >= off) ? sm[tid - off] : 0;
    __syncthreads();
    sm[tid] += v;
    __syncthreads();
  }
  int run = boff[b] + (tid ? sm[tid - 1] : 0);
#pragma unroll
  for (int k = 0; k < 4; ++k) {
    int i = base + k;
    if (i < n) { row_start[i] = run; cursor[i] = run; run += c[k]; }
  }
  if (b == 0 && tid == 0) row_start[n] = E;
}

__global__ void k_scatter(const int* __restrict__ ei, const float* __restrict__ ew,
                          const float* __restrict__ dinv, int* __restrict__ cursor,
                          int2* __restrict__ csr, int E) {
  int e = blockIdx.x * blockDim.x + threadIdx.x;
  if (e < E) {
    int r = ei[e];
    int c = ei[E + e];
    int pos = atomicAdd(cursor + c, 1);
    float w = ew[e] * dinv[r];             // dinv[col] applied at the end
    csr[pos] = make_int2(r, __float_as_int(w));  // single 8B scattered store
  }
}

__global__ void k_convert(const float* __restrict__ X, __half* __restrict__ Xh, long n8) {
  long i = blockIdx.x * (long)blockDim.x + threadIdx.x;
  if (i < n8) {
    const float4* Xv = (const float4*)X;
    float4 a = Xv[2 * i], b = Xv[2 * i + 1];
    union { int4 i4; __half2 h[4]; } u;
    u.h[0] = __floats2half2_rn(a.x, a.y);
    u.h[1] = __floats2half2_rn(a.z, a.w);
    u.h[2] = __floats2half2_rn(b.x, b.y);
    u.h[3] = __floats2half2_rn(b.z, b.w);
    ((int4*)Xh)[i] = u.i4;
  }
}

__global__ __launch_bounds__(1024) void k_prep(
    const float* __restrict__ Wz, const float* __restrict__ bz,
    const float* __restrict__ Wh, const float* __restrict__ bh,
    const float* __restrict__ Lz, const float* __restrict__ lzb,
    const float* __restrict__ Lh, const float* __restrict__ lhb,
    const float* __restrict__ att,
    float* __restrict__ Mt, float* __restrict__ cvec, float* __restrict__ p) {
  int g = blockIdx.x;
  int tid = threadIdx.x;
  const float* L  = g ? Lh  : Lz;
  const float* W  = g ? Wh  : Wz;
  const float* b  = g ? bh  : bz;
  const float* lb = g ? lhb : lzb;
  int f = tid >> 5, o = tid & 31;
  float s = 0.f;
  for (int k = 0; k < 32; ++k) s += L[o * 64 + k] * W[k * 32 + f];
  Mt[g * 1024 + f * 32 + o] = s;
  if (tid < 32) {
    float c = lb[tid];
    for (int k = 0; k < 32; ++k) c += L[tid * 64 + k] * b[k];
    cvec[g * 32 + tid] = c;
  }
  if (g == 0 && tid == 0) {
    float m = att[0];
    for (int t = 1; t < 8; ++t) m = fmaxf(m, att[t]);
    float e8[8], sm = 0.f;
    for (int t = 0; t < 8; ++t) { e8[t] = expf(att[t] - m); sm += e8[t]; }
    for (int t = 0; t < 8; ++t) p[t] = e8[t] / sm;
  }
}

__device__ inline float2 h2f(unsigned u) {
  __half2 h = *(__half2*)&u;
  return __half22float2(h);
}

// One wave per node. fp16 path: lane l owns halves [4l, 4l+4) of the 256-row.
template <bool USE16>
__global__ __launch_bounds__(64) void k_main(
    const float* __restrict__ X, const __half* __restrict__ Xh,
    const int* __restrict__ row_start,
    const int2* __restrict__ csr, const float* __restrict__ dinv,
    const float* __restrict__ Mt, const float* __restrict__ cvec,
    const float* __restrict__ p, float* __restrict__ out) {
  int node = blockIdx.x;
  int l = threadIdx.x;
  __shared__ float ax[256];

  float di = dinv[node];
  float4 acc;
  const uint2*  Xh2 = (const uint2*)Xh;
  const float4* Xv  = (const float4*)X;

  if (USE16) {
    uint2 q = Xh2[(size_t)node * 64 + l];
    float2 f0 = h2f(q.x), f1 = h2f(q.y);
    acc = make_float4(di * f0.x, di * f0.y, di * f1.x, di * f1.y);
  } else {
    float4 a = Xv[(size_t)node * 64 + l];
    acc = make_float4(di * a.x, di * a.y, di * a.z, di * a.w);
  }

  int jlo = row_start[node], jhi = row_start[node + 1];
  int j = jlo;
  for (; j + 3 < jhi; j += 4) {
    int2 e0 = csr[j], e1 = csr[j + 1], e2 = csr[j + 2], e3 = csr[j + 3];
    if (USE16) {
      uint2 q0 = Xh2[(size_t)e0.x * 64 + l];
      uint2 q1 = Xh2[(size_t)e1.x * 64 + l];
      uint2 q2 = Xh2[(size_t)e2.x * 64 + l];
      uint2 q3 = Xh2[(size_t)e3.x * 64 + l];
      float w0 = __int_as_float(e0.y), w1 = __int_as_float(e1.y);
      float w2 = __int_as_float(e2.y), w3 = __int_as_float(e3.y);
      float2 a0 = h2f(q0.x), b0 = h2f(q0.y);
      float2 a1 = h2f(q1.x), b1 = h2f(q1.y);
      float2 a2 = h2f(q2.x), b2 = h2f(q2.y);
      float2 a3 = h2f(q3.x), b3 = h2f(q3.y);
      acc.x = fmaf(w0, a0.x, acc.x); acc.y = fmaf(w0, a0.y, acc.y);
      acc.z = fmaf(w0, b0.x, acc.z); acc.w = fmaf(w0, b0.y, acc.w);
      acc.x = fmaf(w1, a1.x, acc.x); acc.y = fmaf(w1, a1.y, acc.y);
      acc.z = fmaf(w1, b1.x, acc.z); acc.w = fmaf(w1, b1.y, acc.w);
      acc.x = fmaf(w2, a2.x, acc.x); acc.y = fmaf(w2, a2.y, acc.y);
      acc.z = fmaf(w2, b2.x, acc.z); acc.w = fmaf(w2, b2.y, acc.w);
      acc.x = fmaf(w3, a3.x, acc.x); acc.y = fmaf(w3, a3.y, acc.y);
      acc.z = fmaf(w3, b3.x, acc.z); acc.w = fmaf(w3, b3.y, acc.w);
    } else {
      float4 x0 = Xv[(size_t)e0.x * 64 + l];
      float4 x1 = Xv[(size_t)e1.x * 64 + l];
      float4 x2 = Xv[(size_t)e2.x * 64 + l];
      float4 x3 = Xv[(size_t)e3.x * 64 + l];
      float w0 = __int_as_float(e0.y), w1 = __int_as_float(e1.y);
      float w2 = __int_as_float(e2.y), w3 = __int_as_float(e3.y);
      acc.x = fmaf(w0, x0.x, acc.x); acc.y = fmaf(w0, x0.y, acc.y);
      acc.z = fmaf(w0, x0.z, acc.z); acc.w = fmaf(w0, x0.w, acc.w);
      acc.x = fmaf(w1, x1.x, acc.x); acc.y = fmaf(w1, x1.y, acc.y);
      acc.z = fmaf(w1, x1.z, acc.z); acc.w = fmaf(w1, x1.w, acc.w);
      acc.x = fmaf(w2, x2.x, acc.x); acc.y = fmaf(w2, x2.y, acc.y);
      acc.z = fmaf(w2, x2.z, acc.z); acc.w = fmaf(w2, x2.w, acc.w);
      acc.x = fmaf(w3, x3.x, acc.x); acc.y = fmaf(w3, x3.y, acc.y);
      acc.z = fmaf(w3, x3.z, acc.z); acc.w = fmaf(w3, x3.w, acc.w);
    }
  }
  for (; j < jhi; ++j) {
    int2 e0 = csr[j];
    float w0 = __int_as_float(e0.y);
    if (USE16) {
      uint2 q0 = Xh2[(size_t)e0.x * 64 + l];
      float2 a0 = h2f(q0.x), b0 = h2f(q0.y);
      acc.x = fmaf(w0, a0.x, acc.x); acc.y = fmaf(w0, a0.y, acc.y);
      acc.z = fmaf(w0, b0.x, acc.z); acc.w = fmaf(w0, b0.y, acc.w);
    } else {
      float4 x0 = Xv[(size_t)e0.x * 64 + l];
      acc.x = fmaf(w0, x0.x, acc.x); acc.y = fmaf(w0, x0.y, acc.y);
      acc.z = fmaf(w0, x0.z, acc.z); acc.w = fmaf(w0, x0.w, acc.w);
    }
  }
  acc.x *= di; acc.y *= di; acc.z *= di; acc.w *= di;

  ((float4*)ax)[l] = acc;   // ax[f*8 + t]
  __syncthreads();

  int o = l & 31, g = l >> 5;
  float c = cvec[g * 32 + o];
  float pre[8];
#pragma unroll
  for (int t = 0; t < 8; ++t) pre[t] = c;

  const float*  M   = Mt + g * 1024;
  const float4* axv = (const float4*)ax;
#pragma unroll 8
  for (int f = 0; f < 32; ++f) {
    float  m  = M[f * 32 + o];
    float4 a0 = axv[f * 2];
    float4 a1 = axv[f * 2 + 1];
    pre[0] = fmaf(m, a0.x, pre[0]); pre[1] = fmaf(m, a0.y, pre[1]);
    pre[2] = fmaf(m, a0.z, pre[2]); pre[3] = fmaf(m, a0.w, pre[3]);
    pre[4] = fmaf(m, a1.x, pre[4]); pre[5] = fmaf(m, a1.y, pre[5]);
    pre[6] = fmaf(m, a1.z, pre[6]); pre[7] = fmaf(m, a1.w, pre[7]);
  }

  float v[8];
  if (g == 0) {
#pragma unroll
    for (int t = 0; t < 8; ++t) v[t] = 1.f / (1.f + expf(pre[t]));  // 1 - sigmoid
  } else {
#pragma unroll
    for (int t = 0; t < 8; ++t) v[t] = tanhf(pre[t]);
  }

  float pv[8];
#pragma unroll
  for (int t = 0; t < 8; ++t) pv[t] = p[t];

  float res = 0.f;
#pragma unroll
  for (int t = 0; t < 8; ++t) {
    float other = __shfl(v[t], l ^ 32);
    res += pv[t] * v[t] * other;
  }
  if (g == 0) out[(size_t)node * 32 + o] = res;
}

extern "C" void kernel_launch(void* const* d_in, const int* in_sizes, int n_in,
                              void* d_out, int out_size, void* d_ws, size_t ws_size,
                              hipStream_t stream) {
  const float* X   = (const float*)d_in[0];
  const int*   ei  = (const int*)d_in[1];
  const float* ew  = (const float*)d_in[2];
  const float* Wz  = (const float*)d_in[3];
  const float* bz  = (const float*)d_in[4];
  const float* Wh  = (const float*)d_in[7];
  const float* bh  = (const float*)d_in[8];
  const float* Lz  = (const float*)d_in[9];
  const float* lzb = (const float*)d_in[10];
  const float* Lh  = (const float*)d_in[13];
  const float* lhb = (const float*)d_in[14];
  const float* att = (const float*)d_in[15];

  int N = in_sizes[0] / 256;
  int E = in_sizes[2];

  char* w = (char*)d_ws;
  size_t off = 0;
  auto alloc = [&](size_t bytes) -> void* {
    void* pp = w + off;
    off = (off + bytes + 255) & ~(size_t)255;
    return pp;
  };
  unsigned long long* pk = (unsigned long long*)alloc((size_t)N * 8);
  float* dinv      = (float*)alloc((size_t)N * 4);
  int*   row_start = (int*)  alloc((size_t)(N + 1) * 4);
  int*   cursor    = (int*)  alloc((size_t)N * 4);
  int*   bsum      = (int*)  alloc(256 * 4);
  int*   boff      = (int*)  alloc(256 * 4);
  int2*  csr       = (int2*) alloc((size_t)E * 8);
  float* Mt        = (float*)alloc(2048 * 4);
  float* cvec      = (float*)alloc(64 * 4);
  float* p         = (float*)alloc(8 * 4);
  __half* Xh       = (__half*)(w + off);
  size_t need16    = off + (size_t)N * 256 * 2;
  bool use16 = (ws_size >= need16);
  (void)n_in; (void)out_size;

  int nb_n = (N + 255) / 256;
  int nb_e = (E + 255) / 256;
  int nb_b = (N + 1023) / 1024;   // <= 256 for N <= 262144

  if (use16) {
    long n8 = (long)N * 32;       // groups of 8 floats
    k_convert<<<(int)((n8 + 255) / 256), 256, 0, stream>>>(X, Xh, n8);
  }
  k_init   <<<nb_n, 256, 0, stream>>>(pk, N);
  k_count  <<<nb_e, 256, 0, stream>>>(ei, ew, pk, E);
  k_bsum   <<<nb_b, 256, 0, stream>>>(pk, dinv, bsum, N);
  k_bscan  <<<1, 256, 0, stream>>>(bsum, boff, nb_b);
  k_offsets<<<nb_b, 256, 0, stream>>>(pk, boff, row_start, cursor, N, E);
  k_scatter<<<nb_e, 256, 0, stream>>>(ei, ew, dinv, cursor, csr, E);
  k_prep   <<<2, 1024, 0, stream>>>(Wz, bz, Wh, bh, Lz, lzb, Lh, lhb, att,
                                    Mt, cvec, p);
  if (use16)
    k_main<true><<<N, 64, 0, stream>>>(X, Xh, row_start, csr, dinv, Mt, cvec, p,
                                       (float*)d_out);
  else
    k_main<false><<<N, 64, 0, stream>>>(X, Xh, row_start, csr, dinv, Mt, cvec, p,
                                        (float*)d_out);
}